// Round 1
// baseline (967.922 us; speedup 1.0000x reference)
//
#include <hip/hip_runtime.h>

// B=2, S=2048, E=1024, H=16, DH=64, FF=4096.  All dims hardcoded.
// Pipeline (all on `stream`):
//   transpose weights -> bf16 B^T layouts in ws
//   LN1(x) -> nx(bf16)
//   GEMM1: nx @ WqkvT  -> qkv bf16 [4096,3072]   (Q|K|V sections)
//   flash attention (SIMT fp32, online softmax)  -> attn bf16 [4096,1024]
//   GEMM2: attn @ WoT + bo + x -> x1 fp32
//   LN2(x1) -> nx2 bf16
//   GEMM3: relu(nx2 @ W1T + b1) -> h bf16 [4096,4096]
//   GEMM4: h @ W2T + b2 + x1 -> out fp32
// ws usage ~126 MB.

typedef __attribute__((ext_vector_type(8))) short short8;
typedef __attribute__((ext_vector_type(4))) float floatx4;

__device__ inline unsigned short f32_to_bf16(float f) {
  unsigned u = __float_as_uint(f);
  unsigned rb = (u >> 16) & 1u;  // round-to-nearest-even
  u += 0x7fffu + rb;
  return (unsigned short)(u >> 16);
}
__device__ inline float bf16_to_f32(unsigned short u) {
  return __uint_as_float(((unsigned)u) << 16);
}

// ---------------- transpose fp32 [R][C] -> bf16 out[c][r], row stride ldo ---
__global__ __launch_bounds__(256) void transpose_to_bf16(
    const float* __restrict__ in, unsigned short* __restrict__ out,
    int R, int C, int ldo, long in_bs, long out_bs) {
  __shared__ float tile[32][33];
  in  += (size_t)blockIdx.z * in_bs;
  out += (size_t)blockIdx.z * out_bs;
  const int c0 = blockIdx.x * 32, r0 = blockIdx.y * 32;
  const int tx = threadIdx.x & 31, ty = threadIdx.x >> 5;
#pragma unroll
  for (int i = 0; i < 32; i += 8)
    tile[ty + i][tx] = in[(size_t)(r0 + ty + i) * C + c0 + tx];
  __syncthreads();
#pragma unroll
  for (int i = 0; i < 32; i += 8)
    out[(size_t)(c0 + ty + i) * ldo + r0 + tx] = f32_to_bf16(tile[tx][ty + i]);
}

// ---------------- LayerNorm: fp32 [rows][1024] -> bf16, one block per row ---
__global__ __launch_bounds__(256) void layernorm_bf16(
    const float* __restrict__ x, const float* __restrict__ g,
    const float* __restrict__ be, unsigned short* __restrict__ out) {
  const int row = blockIdx.x;
  const int t = threadIdx.x;
  floatx4 v = ((const floatx4*)(x + (size_t)row * 1024))[t];
  float s  = v[0] + v[1] + v[2] + v[3];
  float s2 = v[0]*v[0] + v[1]*v[1] + v[2]*v[2] + v[3]*v[3];
#pragma unroll
  for (int off = 1; off < 64; off <<= 1) {
    s  += __shfl_xor(s, off);
    s2 += __shfl_xor(s2, off);
  }
  __shared__ float red[8];
  const int wave = t >> 6, lane = t & 63;
  if (lane == 0) { red[wave] = s; red[wave + 4] = s2; }
  __syncthreads();
  float ts  = red[0] + red[1] + red[2] + red[3];
  float ts2 = red[4] + red[5] + red[6] + red[7];
  float mu  = ts * (1.f / 1024.f);
  float var = ts2 * (1.f / 1024.f) - mu * mu;
  float rs  = rsqrtf(var + 1e-5f);
  floatx4 gv = ((const floatx4*)g)[t];
  floatx4 bv = ((const floatx4*)be)[t];
  ushort4 ov;
  ov.x = f32_to_bf16((v[0] - mu) * rs * gv[0] + bv[0]);
  ov.y = f32_to_bf16((v[1] - mu) * rs * gv[1] + bv[1]);
  ov.z = f32_to_bf16((v[2] - mu) * rs * gv[2] + bv[2]);
  ov.w = f32_to_bf16((v[3] - mu) * rs * gv[3] + bv[3]);
  ((ushort4*)(out + (size_t)row * 1024))[t] = ov;
}

// ---------------- bf16 MFMA GEMM: C[M,N] = A[M,K] @ Bt[N,K]^T ---------------
// mode 0: store bf16
// mode 1: store fp32, += bias[col] + resid[row*N+col]
// mode 2: store bf16, relu(acc + bias[col])
__global__ __launch_bounds__(256) void gemm_bf16(
    const unsigned short* __restrict__ A, const unsigned short* __restrict__ Bt,
    const float* __restrict__ bias, const float* __restrict__ resid,
    void* __restrict__ Cout, int M, int N, int K, int mode) {
  __shared__ unsigned short As[128][40];  // +8 pad: frag reads ~2-way banked
  __shared__ unsigned short Bs[128][40];
  const int t = threadIdx.x;
  const int m0 = blockIdx.y * 128, n0 = blockIdx.x * 128;
  const int lane = t & 63, wave = t >> 6;
  const int wm = (wave >> 1) * 64, wn = (wave & 1) * 64;
  const int l15 = lane & 15, quad = lane >> 4;

  floatx4 zero = {0.f, 0.f, 0.f, 0.f};
  floatx4 acc[4][4];
#pragma unroll
  for (int i = 0; i < 4; ++i)
#pragma unroll
    for (int j = 0; j < 4; ++j) acc[i][j] = zero;

  // staging: 128x32 bf16 tile = 512 chunks of 8; 2 chunks/thread
  const int ca0 = t, ca1 = t + 256;
  const int r0c = ca0 >> 2, o0c = (ca0 & 3) * 8;
  const int r1c = ca1 >> 2, o1c = (ca1 & 3) * 8;

  const int KT = K >> 5;
  for (int kt = 0; kt < KT; ++kt) {
    __syncthreads();
    const unsigned short* Ag = A + (size_t)m0 * K + kt * 32;
    const unsigned short* Bg = Bt + (size_t)n0 * K + kt * 32;
    *(uint4*)&As[r0c][o0c] = *(const uint4*)(Ag + (size_t)r0c * K + o0c);
    *(uint4*)&As[r1c][o1c] = *(const uint4*)(Ag + (size_t)r1c * K + o1c);
    *(uint4*)&Bs[r0c][o0c] = *(const uint4*)(Bg + (size_t)r0c * K + o0c);
    *(uint4*)&Bs[r1c][o1c] = *(const uint4*)(Bg + (size_t)r1c * K + o1c);
    __syncthreads();
    short8 a[4], b[4];
#pragma unroll
    for (int i = 0; i < 4; ++i)
      a[i] = *(const short8*)&As[wm + i * 16 + l15][quad * 8];
#pragma unroll
    for (int i = 0; i < 4; ++i)
      b[i] = *(const short8*)&Bs[wn + i * 16 + l15][quad * 8];
#pragma unroll
    for (int i = 0; i < 4; ++i)
#pragma unroll
      for (int j = 0; j < 4; ++j)
        acc[i][j] = __builtin_amdgcn_mfma_f32_16x16x32_bf16(a[i], b[j], acc[i][j], 0, 0, 0);
  }

  // epilogue: C/D layout col = lane&15, row = quad*4 + reg  [m89/m91 verified]
#pragma unroll
  for (int i = 0; i < 4; ++i)
#pragma unroll
    for (int j = 0; j < 4; ++j) {
      const int col = n0 + wn + j * 16 + l15;
      const int rb = m0 + wm + i * 16 + quad * 4;
#pragma unroll
      for (int r = 0; r < 4; ++r) {
        const int row = rb + r;
        float v = acc[i][j][r];
        if (mode == 0) {
          ((unsigned short*)Cout)[(size_t)row * N + col] = f32_to_bf16(v);
        } else if (mode == 1) {
          v += bias[col] + resid[(size_t)row * N + col];
          ((float*)Cout)[(size_t)row * N + col] = v;
        } else {
          v += bias[col];
          v = fmaxf(v, 0.f);
          ((unsigned short*)Cout)[(size_t)row * N + col] = f32_to_bf16(v);
        }
      }
    }
}

// ---------------- flash attention (SIMT fp32), causal ----------------------
// qkv bf16 [B*S][3072] (Q|K|V), out attn bf16 [B*S][1024] (col = h*64+d)
// grid (32 qtiles, H, B), 256 threads; thread (ty,tx) owns 4x4 of the 64x64 tile
__global__ __launch_bounds__(256) void flash_attn(
    const unsigned short* __restrict__ qkv, unsigned short* __restrict__ attn) {
  const int b = blockIdx.z, h = blockIdx.y;
  const int qt = (int)gridDim.x - 1 - (int)blockIdx.x;  // big blocks first
  const int q0 = qt * 64;
  __shared__ float Qt[64][64];   // [d][r], pre-scaled by 1/8
  __shared__ float KPt[64][64];  // K as [d][c] during S; reused as P[k][r] for PV
  __shared__ float Vs[64][64];   // [k][c]
  const int t = threadIdx.x;
  const int tx = t & 15, ty = t >> 4;
  const size_t base = (size_t)(b * 2048) * 3072;

  // stage Q (transposed into [d][r])
#pragma unroll
  for (int i = 0; i < 2; ++i) {
    int c = t + 256 * i;
    int sp = c >> 3, d0 = (c & 7) * 8;
    uint4 raw = *(const uint4*)(qkv + base + (size_t)(q0 + sp) * 3072 + h * 64 + d0);
    const unsigned short* us = (const unsigned short*)&raw;
#pragma unroll
    for (int j = 0; j < 8; ++j) Qt[d0 + j][sp] = 0.125f * bf16_to_f32(us[j]);
  }

  float o[4][4];
  float m_old[4], l_old[4];
#pragma unroll
  for (int i = 0; i < 4; ++i) {
    m_old[i] = -1e30f;
    l_old[i] = 0.f;
#pragma unroll
    for (int j = 0; j < 4; ++j) o[i][j] = 0.f;
  }

  for (int kt = 0; kt <= qt; ++kt) {
    const int k0 = kt * 64;
    __syncthreads();  // prior PV reads of KPt/Vs complete
#pragma unroll
    for (int i = 0; i < 2; ++i) {
      int c = t + 256 * i;
      int sp = c >> 3, d0 = (c & 7) * 8;
      uint4 kraw = *(const uint4*)(qkv + base + (size_t)(k0 + sp) * 3072 + 1024 + h * 64 + d0);
      const unsigned short* ku = (const unsigned short*)&kraw;
#pragma unroll
      for (int j = 0; j < 8; ++j) KPt[d0 + j][sp] = bf16_to_f32(ku[j]);
      uint4 vraw = *(const uint4*)(qkv + base + (size_t)(k0 + sp) * 3072 + 2048 + h * 64 + d0);
      const unsigned short* vu = (const unsigned short*)&vraw;
      floatx4 v0 = {bf16_to_f32(vu[0]), bf16_to_f32(vu[1]), bf16_to_f32(vu[2]), bf16_to_f32(vu[3])};
      floatx4 v1 = {bf16_to_f32(vu[4]), bf16_to_f32(vu[5]), bf16_to_f32(vu[6]), bf16_to_f32(vu[7])};
      *(floatx4*)&Vs[sp][d0] = v0;
      *(floatx4*)&Vs[sp][d0 + 4] = v1;
    }
    __syncthreads();

    // S = Q K^T (4x4 micro-tile per thread)
    float s[4][4];
#pragma unroll
    for (int i = 0; i < 4; ++i)
#pragma unroll
      for (int j = 0; j < 4; ++j) s[i][j] = 0.f;
    for (int d = 0; d < 64; ++d) {
      floatx4 qv = *(const floatx4*)&Qt[d][ty * 4];
      floatx4 kv = *(const floatx4*)&KPt[d][tx * 4];
#pragma unroll
      for (int i = 0; i < 4; ++i)
#pragma unroll
        for (int j = 0; j < 4; ++j) s[i][j] += qv[i] * kv[j];
    }
    if (kt == qt) {
#pragma unroll
      for (int i = 0; i < 4; ++i)
#pragma unroll
        for (int j = 0; j < 4; ++j)
          if (tx * 4 + j > ty * 4 + i) s[i][j] = -1e30f;
    }

    // online softmax: row stats across the 16 tx lanes (same wave)
    float pm[4];
#pragma unroll
    for (int i = 0; i < 4; ++i)
      pm[i] = fmaxf(fmaxf(s[i][0], s[i][1]), fmaxf(s[i][2], s[i][3]));
#pragma unroll
    for (int off = 1; off < 16; off <<= 1)
#pragma unroll
      for (int i = 0; i < 4; ++i) pm[i] = fmaxf(pm[i], __shfl_xor(pm[i], off));

    float mnew[4], alpha[4], psum[4];
#pragma unroll
    for (int i = 0; i < 4; ++i) {
      mnew[i] = fmaxf(m_old[i], pm[i]);
      alpha[i] = __expf(m_old[i] - mnew[i]);
    }
    float p[4][4];
#pragma unroll
    for (int i = 0; i < 4; ++i) {
      float a = 0.f;
#pragma unroll
      for (int j = 0; j < 4; ++j) {
        p[i][j] = __expf(s[i][j] - mnew[i]);
        a += p[i][j];
      }
      psum[i] = a;
    }
#pragma unroll
    for (int off = 1; off < 16; off <<= 1)
#pragma unroll
      for (int i = 0; i < 4; ++i) psum[i] += __shfl_xor(psum[i], off);

    __syncthreads();  // all S reads of KPt done -> safe to overwrite with P
#pragma unroll
    for (int i = 0; i < 4; ++i)
#pragma unroll
      for (int j = 0; j < 4; ++j) KPt[tx * 4 + j][ty * 4 + i] = p[i][j];  // P[k][r]
#pragma unroll
    for (int i = 0; i < 4; ++i) {
      l_old[i] = l_old[i] * alpha[i] + psum[i];
      m_old[i] = mnew[i];
#pragma unroll
      for (int j = 0; j < 4; ++j) o[i][j] *= alpha[i];
    }
    __syncthreads();  // P visible

    // O += P V
    for (int k = 0; k < 64; ++k) {
      floatx4 pv = *(const floatx4*)&KPt[k][ty * 4];
      floatx4 vv = *(const floatx4*)&Vs[k][tx * 4];
#pragma unroll
      for (int i = 0; i < 4; ++i)
#pragma unroll
        for (int j = 0; j < 4; ++j) o[i][j] += pv[i] * vv[j];
    }
  }

#pragma unroll
  for (int i = 0; i < 4; ++i) {
    float rl = 1.f / l_old[i];
    const int row = b * 2048 + q0 + ty * 4 + i;
#pragma unroll
    for (int j = 0; j < 4; ++j)
      attn[(size_t)row * 1024 + h * 64 + tx * 4 + j] = f32_to_bf16(o[i][j] * rl);
  }
}

// ---------------------------------------------------------------------------
extern "C" void kernel_launch(void* const* d_in, const int* in_sizes, int n_in,
                              void* d_out, int out_size, void* d_ws, size_t ws_size,
                              hipStream_t stream) {
  const float* x   = (const float*)d_in[0];
  const float* Wq  = (const float*)d_in[1];
  const float* Wk  = (const float*)d_in[2];
  const float* Wv  = (const float*)d_in[3];
  const float* Wo  = (const float*)d_in[4];
  const float* bo  = (const float*)d_in[5];
  const float* W1  = (const float*)d_in[6];
  const float* b1  = (const float*)d_in[7];
  const float* W2  = (const float*)d_in[8];
  const float* b2  = (const float*)d_in[9];
  const float* g1  = (const float*)d_in[10];
  const float* be1 = (const float*)d_in[11];
  const float* g2  = (const float*)d_in[12];
  const float* be2 = (const float*)d_in[13];
  float* out = (float*)d_out;

  char* ws = (char*)d_ws;
  size_t off = 0;
  auto alloc = [&](size_t bytes) -> void* {
    void* p = ws + off;
    off += (bytes + 255) & ~(size_t)255;
    return p;
  };
  unsigned short* WqkvT = (unsigned short*)alloc(3072ull * 1024 * 2);
  unsigned short* WoT   = (unsigned short*)alloc(1024ull * 1024 * 2);
  unsigned short* W1T   = (unsigned short*)alloc(4096ull * 1024 * 2);
  unsigned short* W2T   = (unsigned short*)alloc(1024ull * 4096 * 2);
  unsigned short* nx    = (unsigned short*)alloc(4096ull * 1024 * 2);
  unsigned short* qkv   = (unsigned short*)alloc(4096ull * 3072 * 2);
  unsigned short* attn  = (unsigned short*)alloc(4096ull * 1024 * 2);
  float*          x1    = (float*)alloc(4096ull * 1024 * 4);
  unsigned short* nx2   = (unsigned short*)alloc(4096ull * 1024 * 2);
  unsigned short* hbuf  = (unsigned short*)alloc(4096ull * 4096 * 2);

  dim3 blk(256);
  // weight transposes: Wq/Wk/Wv [16][1024][64] -> WqkvT rows h*64+d
  transpose_to_bf16<<<dim3(2, 32, 16), blk, 0, stream>>>(Wq, WqkvT, 1024, 64, 1024, 65536, 65536);
  transpose_to_bf16<<<dim3(2, 32, 16), blk, 0, stream>>>(Wk, WqkvT + 1024 * 1024, 1024, 64, 1024, 65536, 65536);
  transpose_to_bf16<<<dim3(2, 32, 16), blk, 0, stream>>>(Wv, WqkvT + 2 * 1024 * 1024, 1024, 64, 1024, 65536, 65536);
  transpose_to_bf16<<<dim3(32, 32, 1), blk, 0, stream>>>(Wo, WoT, 1024, 1024, 1024, 0, 0);
  transpose_to_bf16<<<dim3(128, 32, 1), blk, 0, stream>>>(W1, W1T, 1024, 4096, 1024, 0, 0);
  transpose_to_bf16<<<dim3(32, 128, 1), blk, 0, stream>>>(W2, W2T, 4096, 1024, 4096, 0, 0);

  layernorm_bf16<<<4096, blk, 0, stream>>>(x, g1, be1, nx);
  gemm_bf16<<<dim3(24, 32), blk, 0, stream>>>(nx, WqkvT, nullptr, nullptr, qkv, 4096, 3072, 1024, 0);
  flash_attn<<<dim3(32, 16, 2), blk, 0, stream>>>(qkv, attn);
  gemm_bf16<<<dim3(8, 32), blk, 0, stream>>>(attn, WoT, bo, x, x1, 4096, 1024, 1024, 1);
  layernorm_bf16<<<4096, blk, 0, stream>>>(x1, g2, be2, nx2);
  gemm_bf16<<<dim3(32, 32), blk, 0, stream>>>(nx2, W1T, b1, nullptr, hbuf, 4096, 4096, 1024, 2);
  gemm_bf16<<<dim3(8, 32), blk, 0, stream>>>(hbuf, W2T, b2, x1, out, 4096, 1024, 4096, 1);
}

// Round 3
// 514.743 us; speedup vs baseline: 1.8804x; 1.8804x over previous
//
#include <hip/hip_runtime.h>

// B=2, S=2048, E=1024, H=16, DH=64, FF=4096.  All dims hardcoded.
// Pipeline:
//   transpose weights -> bf16 B^T layouts in ws
//   LN1(x) -> nx(bf16)
//   GEMM1: nx @ WqkvT  -> qkv bf16 [4096,3072]   (Q|K|V sections)
//   transpose V section -> vT[bh][64][2048]
//   MFMA flash attention -> attn bf16 [4096,1024]
//   GEMM2: attn @ WoT + bo + x -> x1 fp32
//   LN2(x1) -> nx2 bf16
//   GEMM3: relu(nx2 @ W1T + b1) -> h bf16
//   GEMM4: h @ W2T + b2 + x1 -> out fp32

typedef __attribute__((ext_vector_type(8))) short short8;
typedef __attribute__((ext_vector_type(4))) float floatx4;

__device__ inline unsigned short f32_to_bf16(float f) {
  unsigned u = __float_as_uint(f);
  unsigned rb = (u >> 16) & 1u;  // round-to-nearest-even
  u += 0x7fffu + rb;
  return (unsigned short)(u >> 16);
}
__device__ inline float bf16_to_f32(unsigned short u) {
  return __uint_as_float(((unsigned)u) << 16);
}

// ---------------- transpose fp32 [R][C] -> bf16 out[c][r], row stride ldo ---
__global__ __launch_bounds__(256) void transpose_to_bf16(
    const float* __restrict__ in, unsigned short* __restrict__ out,
    int R, int C, int ldo, long in_bs, long out_bs) {
  __shared__ float tile[32][33];
  in  += (size_t)blockIdx.z * in_bs;
  out += (size_t)blockIdx.z * out_bs;
  const int c0 = blockIdx.x * 32, r0 = blockIdx.y * 32;
  const int tx = threadIdx.x & 31, ty = threadIdx.x >> 5;
#pragma unroll
  for (int i = 0; i < 32; i += 8)
    tile[ty + i][tx] = in[(size_t)(r0 + ty + i) * C + c0 + tx];
  __syncthreads();
#pragma unroll
  for (int i = 0; i < 32; i += 8)
    out[(size_t)(c0 + ty + i) * ldo + r0 + tx] = f32_to_bf16(tile[tx][ty + i]);
}

// ---------------- transpose V section of qkv (bf16) -> vT[bh*64+d][2048] ----
__global__ __launch_bounds__(256) void transpose_v(
    const unsigned short* __restrict__ qkv, unsigned short* __restrict__ vT) {
  __shared__ unsigned short tile[32][33];
  const int bh = blockIdx.z, b = bh >> 4, h = bh & 15;
  const int k0 = blockIdx.x * 32, d0 = blockIdx.y * 32;
  const int tx = threadIdx.x & 31, ty = threadIdx.x >> 5;
#pragma unroll
  for (int i = 0; i < 32; i += 8)
    tile[ty + i][tx] = qkv[(size_t)(b * 2048 + k0 + ty + i) * 3072 + 2048 + h * 64 + d0 + tx];
  __syncthreads();
#pragma unroll
  for (int i = 0; i < 32; i += 8)
    vT[((size_t)bh * 64 + d0 + ty + i) * 2048 + k0 + tx] = tile[tx][ty + i];
}

// ---------------- LayerNorm: fp32 [rows][1024] -> bf16, one block per row ---
__global__ __launch_bounds__(256) void layernorm_bf16(
    const float* __restrict__ x, const float* __restrict__ g,
    const float* __restrict__ be, unsigned short* __restrict__ out) {
  const int row = blockIdx.x;
  const int t = threadIdx.x;
  floatx4 v = ((const floatx4*)(x + (size_t)row * 1024))[t];
  float s  = v[0] + v[1] + v[2] + v[3];
  float s2 = v[0]*v[0] + v[1]*v[1] + v[2]*v[2] + v[3]*v[3];
#pragma unroll
  for (int off = 1; off < 64; off <<= 1) {
    s  += __shfl_xor(s, off);
    s2 += __shfl_xor(s2, off);
  }
  __shared__ float red[8];
  const int wave = t >> 6, lane = t & 63;
  if (lane == 0) { red[wave] = s; red[wave + 4] = s2; }
  __syncthreads();
  float ts  = red[0] + red[1] + red[2] + red[3];
  float ts2 = red[4] + red[5] + red[6] + red[7];
  float mu  = ts * (1.f / 1024.f);
  float var = ts2 * (1.f / 1024.f) - mu * mu;
  float rs  = rsqrtf(var + 1e-5f);
  floatx4 gv = ((const floatx4*)g)[t];
  floatx4 bv = ((const floatx4*)be)[t];
  ushort4 ov;
  ov.x = f32_to_bf16((v[0] - mu) * rs * gv[0] + bv[0]);
  ov.y = f32_to_bf16((v[1] - mu) * rs * gv[1] + bv[1]);
  ov.z = f32_to_bf16((v[2] - mu) * rs * gv[2] + bv[2]);
  ov.w = f32_to_bf16((v[3] - mu) * rs * gv[3] + bv[3]);
  ((ushort4*)(out + (size_t)row * 1024))[t] = ov;
}

// ---------------- bf16 MFMA GEMM: C[M,N] = A[M,K] @ Bt[N,K]^T ---------------
__global__ __launch_bounds__(256) void gemm_bf16(
    const unsigned short* __restrict__ A, const unsigned short* __restrict__ Bt,
    const float* __restrict__ bias, const float* __restrict__ resid,
    void* __restrict__ Cout, int M, int N, int K, int mode) {
  __shared__ unsigned short As[128][40];
  __shared__ unsigned short Bs[128][40];
  const int t = threadIdx.x;
  const int m0 = blockIdx.y * 128, n0 = blockIdx.x * 128;
  const int lane = t & 63, wave = t >> 6;
  const int wm = (wave >> 1) * 64, wn = (wave & 1) * 64;
  const int l15 = lane & 15, quad = lane >> 4;

  floatx4 zero = {0.f, 0.f, 0.f, 0.f};
  floatx4 acc[4][4];
#pragma unroll
  for (int i = 0; i < 4; ++i)
#pragma unroll
    for (int j = 0; j < 4; ++j) acc[i][j] = zero;

  const int ca0 = t, ca1 = t + 256;
  const int r0c = ca0 >> 2, o0c = (ca0 & 3) * 8;
  const int r1c = ca1 >> 2, o1c = (ca1 & 3) * 8;

  const int KT = K >> 5;
  for (int kt = 0; kt < KT; ++kt) {
    __syncthreads();
    const unsigned short* Ag = A + (size_t)m0 * K + kt * 32;
    const unsigned short* Bg = Bt + (size_t)n0 * K + kt * 32;
    *(uint4*)&As[r0c][o0c] = *(const uint4*)(Ag + (size_t)r0c * K + o0c);
    *(uint4*)&As[r1c][o1c] = *(const uint4*)(Ag + (size_t)r1c * K + o1c);
    *(uint4*)&Bs[r0c][o0c] = *(const uint4*)(Bg + (size_t)r0c * K + o0c);
    *(uint4*)&Bs[r1c][o1c] = *(const uint4*)(Bg + (size_t)r1c * K + o1c);
    __syncthreads();
    short8 a[4], b[4];
#pragma unroll
    for (int i = 0; i < 4; ++i)
      a[i] = *(const short8*)&As[wm + i * 16 + l15][quad * 8];
#pragma unroll
    for (int i = 0; i < 4; ++i)
      b[i] = *(const short8*)&Bs[wn + i * 16 + l15][quad * 8];
#pragma unroll
    for (int i = 0; i < 4; ++i)
#pragma unroll
      for (int j = 0; j < 4; ++j)
        acc[i][j] = __builtin_amdgcn_mfma_f32_16x16x32_bf16(a[i], b[j], acc[i][j], 0, 0, 0);
  }

#pragma unroll
  for (int i = 0; i < 4; ++i)
#pragma unroll
    for (int j = 0; j < 4; ++j) {
      const int col = n0 + wn + j * 16 + l15;
      const int rb = m0 + wm + i * 16 + quad * 4;
#pragma unroll
      for (int r = 0; r < 4; ++r) {
        const int row = rb + r;
        float v = acc[i][j][r];
        if (mode == 0) {
          ((unsigned short*)Cout)[(size_t)row * N + col] = f32_to_bf16(v);
        } else if (mode == 1) {
          v += bias[col] + resid[(size_t)row * N + col];
          ((float*)Cout)[(size_t)row * N + col] = v;
        } else {
          v += bias[col];
          v = fmaxf(v, 0.f);
          ((unsigned short*)Cout)[(size_t)row * N + col] = f32_to_bf16(v);
        }
      }
    }
}

// ---------------- MFMA flash attention, causal ------------------------------
// Block: 128 q-rows, 4 waves x 32 rows. K-tile = 64 keys staged in LDS.
// Q frags in registers (scaled by 1/8). P via per-wave LDS (no barrier).
__global__ __launch_bounds__(256, 3) void flash_attn_mfma(
    const unsigned short* __restrict__ qkv,
    const unsigned short* __restrict__ vT,
    unsigned short* __restrict__ attn) {
  const int b = blockIdx.z, h = blockIdx.y, bh = b * 16 + h;
  const int qt = 15 - (int)blockIdx.x;  // biggest first
  const int q0 = qt * 128;
  const int t = threadIdx.x;
  const int wave = t >> 6, lane = t & 63;
  const int l15 = lane & 15, quad = lane >> 4;

  __shared__ unsigned short Ks[64][72];  // [key][d]
  __shared__ unsigned short Vt[64][72];  // [d][key]
  __shared__ unsigned short Ps[4][32][72];  // per-wave P [q][key]

  const size_t qbase = (size_t)b * 2048 * 3072;
  const int qrow_w = q0 + wave * 32;

  // Q A-frags from global: A[m=l15][k=quad*8+j], chunks kc*32; scale 1/8 exact
  short8 qf[2][2];
#pragma unroll
  for (int mf = 0; mf < 2; ++mf)
#pragma unroll
    for (int kc = 0; kc < 2; ++kc) {
      short8 raw = *(const short8*)(qkv + qbase +
          (size_t)(qrow_w + mf * 16 + l15) * 3072 + h * 64 + kc * 32 + quad * 8);
      short8 sc;
#pragma unroll
      for (int j = 0; j < 8; ++j)
        sc[j] = (short)f32_to_bf16(bf16_to_f32((unsigned short)raw[j]) * 0.125f);
      qf[mf][kc] = sc;
    }

  floatx4 o[2][4];
  float m_s[2][4], l_s[2][4];
#pragma unroll
  for (int mf = 0; mf < 2; ++mf)
#pragma unroll
    for (int r = 0; r < 4; ++r) {
      m_s[mf][r] = -1e30f;
      l_s[mf][r] = 0.f;
#pragma unroll
      for (int jd = 0; jd < 4; ++jd) o[mf][jd][r] = 0.f;
    }

  const int sr = t >> 3, so = (t & 7) * 8;  // staging: rows sr, sr+32, 8-short chunks

  const int ntiles = 2 * qt + 2;
  for (int kt = 0; kt < ntiles; ++kt) {
    const int k0 = kt * 64;
    __syncthreads();
    *(uint4*)&Ks[sr][so]      = *(const uint4*)(qkv + qbase + (size_t)(k0 + sr) * 3072 + 1024 + h * 64 + so);
    *(uint4*)&Ks[sr + 32][so] = *(const uint4*)(qkv + qbase + (size_t)(k0 + sr + 32) * 3072 + 1024 + h * 64 + so);
    *(uint4*)&Vt[sr][so]      = *(const uint4*)(vT + ((size_t)bh * 64 + sr) * 2048 + k0 + so);
    *(uint4*)&Vt[sr + 32][so] = *(const uint4*)(vT + ((size_t)bh * 64 + sr + 32) * 2048 + k0 + so);
    __syncthreads();
    if (k0 > qrow_w + 31) continue;  // wave-uniform: no rows need this tile

    // S = Q K^T : 16 MFMAs
    floatx4 sacc[2][4];
#pragma unroll
    for (int mf = 0; mf < 2; ++mf)
#pragma unroll
      for (int jb = 0; jb < 4; ++jb) sacc[mf][jb] = floatx4{0.f, 0.f, 0.f, 0.f};
#pragma unroll
    for (int kc = 0; kc < 2; ++kc)
#pragma unroll
      for (int jb = 0; jb < 4; ++jb) {
        short8 bf = *(const short8*)&Ks[jb * 16 + l15][kc * 32 + quad * 8];
#pragma unroll
        for (int mf = 0; mf < 2; ++mf)
          sacc[mf][jb] = __builtin_amdgcn_mfma_f32_16x16x32_bf16(qf[mf][kc], bf, sacc[mf][jb], 0, 0, 0);
      }

    // causal mask (only tiles near the diagonal)
    if (k0 + 63 > qrow_w) {
#pragma unroll
      for (int mf = 0; mf < 2; ++mf)
#pragma unroll
        for (int jb = 0; jb < 4; ++jb) {
          const int key = k0 + jb * 16 + l15;
          const int rowb = qrow_w + mf * 16 + quad * 4;
#pragma unroll
          for (int r = 0; r < 4; ++r)
            if (key > rowb + r) sacc[mf][jb][r] = -1e30f;
        }
    }

    // online softmax: stats per (mf,r) row, reduce across 16 lanes
    float mx[2][4];
#pragma unroll
    for (int mf = 0; mf < 2; ++mf)
#pragma unroll
      for (int r = 0; r < 4; ++r)
        mx[mf][r] = fmaxf(fmaxf(sacc[mf][0][r], sacc[mf][1][r]),
                          fmaxf(sacc[mf][2][r], sacc[mf][3][r]));
#pragma unroll
    for (int off = 1; off < 16; off <<= 1)
#pragma unroll
      for (int mf = 0; mf < 2; ++mf)
#pragma unroll
        for (int r = 0; r < 4; ++r) mx[mf][r] = fmaxf(mx[mf][r], __shfl_xor(mx[mf][r], off));

    float alpha[2][4], ls[2][4];
#pragma unroll
    for (int mf = 0; mf < 2; ++mf)
#pragma unroll
      for (int r = 0; r < 4; ++r) {
        float mn = fmaxf(m_s[mf][r], mx[mf][r]);
        alpha[mf][r] = __expf(m_s[mf][r] - mn);
        m_s[mf][r] = mn;
        ls[mf][r] = 0.f;
      }
#pragma unroll
    for (int mf = 0; mf < 2; ++mf)
#pragma unroll
      for (int jb = 0; jb < 4; ++jb)
#pragma unroll
        for (int r = 0; r < 4; ++r) {
          float p = __expf(sacc[mf][jb][r] - m_s[mf][r]);
          sacc[mf][jb][r] = p;
          ls[mf][r] += p;
        }
#pragma unroll
    for (int off = 1; off < 16; off <<= 1)
#pragma unroll
      for (int mf = 0; mf < 2; ++mf)
#pragma unroll
        for (int r = 0; r < 4; ++r) ls[mf][r] += __shfl_xor(ls[mf][r], off);
#pragma unroll
    for (int mf = 0; mf < 2; ++mf)
#pragma unroll
      for (int r = 0; r < 4; ++r) l_s[mf][r] = l_s[mf][r] * alpha[mf][r] + ls[mf][r];
#pragma unroll
    for (int mf = 0; mf < 2; ++mf)
#pragma unroll
      for (int jd = 0; jd < 4; ++jd)
#pragma unroll
        for (int r = 0; r < 4; ++r) o[mf][jd][r] *= alpha[mf][r];

    // P -> per-wave LDS (bf16), C-layout scatter; same-wave DS ops are
    // in-order, so no barrier needed between write and read
#pragma unroll
    for (int mf = 0; mf < 2; ++mf)
#pragma unroll
      for (int jb = 0; jb < 4; ++jb)
#pragma unroll
        for (int r = 0; r < 4; ++r)
          Ps[wave][mf * 16 + quad * 4 + r][jb * 16 + l15] = f32_to_bf16(sacc[mf][jb][r]);

    // O += P V : 16 MFMAs
#pragma unroll
    for (int kc = 0; kc < 2; ++kc) {
      short8 pf0 = *(const short8*)&Ps[wave][l15][kc * 32 + quad * 8];
      short8 pf1 = *(const short8*)&Ps[wave][16 + l15][kc * 32 + quad * 8];
#pragma unroll
      for (int jd = 0; jd < 4; ++jd) {
        short8 vf = *(const short8*)&Vt[jd * 16 + l15][kc * 32 + quad * 8];
        o[0][jd] = __builtin_amdgcn_mfma_f32_16x16x32_bf16(pf0, vf, o[0][jd], 0, 0, 0);
        o[1][jd] = __builtin_amdgcn_mfma_f32_16x16x32_bf16(pf1, vf, o[1][jd], 0, 0, 0);
      }
    }
  }

  // epilogue: note the b*2048 batch offset (R2 bug: it was missing)
#pragma unroll
  for (int mf = 0; mf < 2; ++mf)
#pragma unroll
    for (int r = 0; r < 4; ++r) {
      const int row = b * 2048 + qrow_w + mf * 16 + quad * 4 + r;
      const float rl = 1.f / l_s[mf][r];
#pragma unroll
      for (int jd = 0; jd < 4; ++jd)
        attn[(size_t)row * 1024 + h * 64 + jd * 16 + l15] = f32_to_bf16(o[mf][jd][r] * rl);
    }
}

// ---------------------------------------------------------------------------
extern "C" void kernel_launch(void* const* d_in, const int* in_sizes, int n_in,
                              void* d_out, int out_size, void* d_ws, size_t ws_size,
                              hipStream_t stream) {
  const float* x   = (const float*)d_in[0];
  const float* Wq  = (const float*)d_in[1];
  const float* Wk  = (const float*)d_in[2];
  const float* Wv  = (const float*)d_in[3];
  const float* Wo  = (const float*)d_in[4];
  const float* bo  = (const float*)d_in[5];
  const float* W1  = (const float*)d_in[6];
  const float* b1  = (const float*)d_in[7];
  const float* W2  = (const float*)d_in[8];
  const float* b2  = (const float*)d_in[9];
  const float* g1  = (const float*)d_in[10];
  const float* be1 = (const float*)d_in[11];
  const float* g2  = (const float*)d_in[12];
  const float* be2 = (const float*)d_in[13];
  float* out = (float*)d_out;

  char* ws = (char*)d_ws;
  size_t off = 0;
  auto alloc = [&](size_t bytes) -> void* {
    void* p = ws + off;
    off += (bytes + 255) & ~(size_t)255;
    return p;
  };
  unsigned short* WqkvT = (unsigned short*)alloc(3072ull * 1024 * 2);
  unsigned short* WoT   = (unsigned short*)alloc(1024ull * 1024 * 2);
  unsigned short* W1T   = (unsigned short*)alloc(4096ull * 1024 * 2);
  unsigned short* W2T   = (unsigned short*)alloc(1024ull * 4096 * 2);
  unsigned short* nx    = (unsigned short*)alloc(4096ull * 1024 * 2);
  unsigned short* qkv   = (unsigned short*)alloc(4096ull * 3072 * 2);
  unsigned short* attn  = (unsigned short*)alloc(4096ull * 1024 * 2);
  float*          x1    = (float*)alloc(4096ull * 1024 * 4);
  unsigned short* nx2   = (unsigned short*)alloc(4096ull * 1024 * 2);
  unsigned short* hbuf  = (unsigned short*)alloc(4096ull * 4096 * 2);
  // vT [32][64][2048] bf16 (8 MB) aliases hbuf: vT dead before GEMM3 writes hbuf
  unsigned short* vT    = hbuf;

  dim3 blk(256);
  transpose_to_bf16<<<dim3(2, 32, 16), blk, 0, stream>>>(Wq, WqkvT, 1024, 64, 1024, 65536, 65536);
  transpose_to_bf16<<<dim3(2, 32, 16), blk, 0, stream>>>(Wk, WqkvT + 1024 * 1024, 1024, 64, 1024, 65536, 65536);
  transpose_to_bf16<<<dim3(2, 32, 16), blk, 0, stream>>>(Wv, WqkvT + 2 * 1024 * 1024, 1024, 64, 1024, 65536, 65536);
  transpose_to_bf16<<<dim3(32, 32, 1), blk, 0, stream>>>(Wo, WoT, 1024, 1024, 1024, 0, 0);
  transpose_to_bf16<<<dim3(128, 32, 1), blk, 0, stream>>>(W1, W1T, 1024, 4096, 1024, 0, 0);
  transpose_to_bf16<<<dim3(32, 128, 1), blk, 0, stream>>>(W2, W2T, 4096, 1024, 4096, 0, 0);

  layernorm_bf16<<<4096, blk, 0, stream>>>(x, g1, be1, nx);
  gemm_bf16<<<dim3(24, 32), blk, 0, stream>>>(nx, WqkvT, nullptr, nullptr, qkv, 4096, 3072, 1024, 0);
  transpose_v<<<dim3(64, 2, 32), blk, 0, stream>>>(qkv, vT);
  flash_attn_mfma<<<dim3(16, 16, 2), blk, 0, stream>>>(qkv, vT, attn);
  gemm_bf16<<<dim3(8, 32), blk, 0, stream>>>(attn, WoT, bo, x, x1, 4096, 1024, 1024, 1);
  layernorm_bf16<<<4096, blk, 0, stream>>>(x1, g2, be2, nx2);
  gemm_bf16<<<dim3(32, 32), blk, 0, stream>>>(nx2, W1T, b1, nullptr, hbuf, 4096, 4096, 1024, 2);
  gemm_bf16<<<dim3(8, 32), blk, 0, stream>>>(hbuf, W2T, b2, x1, out, 4096, 1024, 4096, 1);
}

// Round 4
// 510.990 us; speedup vs baseline: 1.8942x; 1.0073x over previous
//
#include <hip/hip_runtime.h>

// B=2, S=2048, E=1024, H=16, DH=64, FF=4096.  All dims hardcoded.
// Pipeline:
//   transpose weights -> bf16 B^T layouts in ws
//   LN1(x) -> nx(bf16)
//   GEMM1: nx @ WqkvT  -> qkv bf16 [4096,3072]   (Q|K|V sections)
//   transpose V section -> vT[bh][64][2048]
//   MFMA flash attention -> attn bf16 [4096,1024]
//   GEMM2: attn @ WoT + bo + x -> x1 fp32
//   LN2(x1) -> nx2 bf16
//   GEMM3: relu(nx2 @ W1T + b1) -> h bf16
//   GEMM4: h @ W2T + b2 + x1 -> out fp32
// R4: gemm_bf16 staging switched to global_load_lds width-16 (m93->m97 step).

typedef __attribute__((ext_vector_type(8))) short short8;
typedef __attribute__((ext_vector_type(4))) float floatx4;

__device__ inline unsigned short f32_to_bf16(float f) {
  unsigned u = __float_as_uint(f);
  unsigned rb = (u >> 16) & 1u;  // round-to-nearest-even
  u += 0x7fffu + rb;
  return (unsigned short)(u >> 16);
}
__device__ inline float bf16_to_f32(unsigned short u) {
  return __uint_as_float(((unsigned)u) << 16);
}

// async global->LDS, 16 B per lane; lds dest must be wave-uniform base,
// HW scatters lane i to base + i*16 [m97/m104]
__device__ inline void gl2lds16(const unsigned short* g, unsigned short* lds) {
  __builtin_amdgcn_global_load_lds(
      (const __attribute__((address_space(1))) unsigned*)g,
      (__attribute__((address_space(3))) unsigned*)lds, 16, 0, 0);
}

// ---------------- transpose fp32 [R][C] -> bf16 out[c][r], row stride ldo ---
__global__ __launch_bounds__(256) void transpose_to_bf16(
    const float* __restrict__ in, unsigned short* __restrict__ out,
    int R, int C, int ldo, long in_bs, long out_bs) {
  __shared__ float tile[32][33];
  in  += (size_t)blockIdx.z * in_bs;
  out += (size_t)blockIdx.z * out_bs;
  const int c0 = blockIdx.x * 32, r0 = blockIdx.y * 32;
  const int tx = threadIdx.x & 31, ty = threadIdx.x >> 5;
#pragma unroll
  for (int i = 0; i < 32; i += 8)
    tile[ty + i][tx] = in[(size_t)(r0 + ty + i) * C + c0 + tx];
  __syncthreads();
#pragma unroll
  for (int i = 0; i < 32; i += 8)
    out[(size_t)(c0 + ty + i) * ldo + r0 + tx] = f32_to_bf16(tile[tx][ty + i]);
}

// ---------------- transpose V section of qkv (bf16) -> vT[bh*64+d][2048] ----
__global__ __launch_bounds__(256) void transpose_v(
    const unsigned short* __restrict__ qkv, unsigned short* __restrict__ vT) {
  __shared__ unsigned short tile[32][33];
  const int bh = blockIdx.z, b = bh >> 4, h = bh & 15;
  const int k0 = blockIdx.x * 32, d0 = blockIdx.y * 32;
  const int tx = threadIdx.x & 31, ty = threadIdx.x >> 5;
#pragma unroll
  for (int i = 0; i < 32; i += 8)
    tile[ty + i][tx] = qkv[(size_t)(b * 2048 + k0 + ty + i) * 3072 + 2048 + h * 64 + d0 + tx];
  __syncthreads();
#pragma unroll
  for (int i = 0; i < 32; i += 8)
    vT[((size_t)bh * 64 + d0 + ty + i) * 2048 + k0 + tx] = tile[tx][ty + i];
}

// ---------------- LayerNorm: fp32 [rows][1024] -> bf16, one block per row ---
__global__ __launch_bounds__(256) void layernorm_bf16(
    const float* __restrict__ x, const float* __restrict__ g,
    const float* __restrict__ be, unsigned short* __restrict__ out) {
  const int row = blockIdx.x;
  const int t = threadIdx.x;
  floatx4 v = ((const floatx4*)(x + (size_t)row * 1024))[t];
  float s  = v[0] + v[1] + v[2] + v[3];
  float s2 = v[0]*v[0] + v[1]*v[1] + v[2]*v[2] + v[3]*v[3];
#pragma unroll
  for (int off = 1; off < 64; off <<= 1) {
    s  += __shfl_xor(s, off);
    s2 += __shfl_xor(s2, off);
  }
  __shared__ float red[8];
  const int wave = t >> 6, lane = t & 63;
  if (lane == 0) { red[wave] = s; red[wave + 4] = s2; }
  __syncthreads();
  float ts  = red[0] + red[1] + red[2] + red[3];
  float ts2 = red[4] + red[5] + red[6] + red[7];
  float mu  = ts * (1.f / 1024.f);
  float var = ts2 * (1.f / 1024.f) - mu * mu;
  float rs  = rsqrtf(var + 1e-5f);
  floatx4 gv = ((const floatx4*)g)[t];
  floatx4 bv = ((const floatx4*)be)[t];
  ushort4 ov;
  ov.x = f32_to_bf16((v[0] - mu) * rs * gv[0] + bv[0]);
  ov.y = f32_to_bf16((v[1] - mu) * rs * gv[1] + bv[1]);
  ov.z = f32_to_bf16((v[2] - mu) * rs * gv[2] + bv[2]);
  ov.w = f32_to_bf16((v[3] - mu) * rs * gv[3] + bv[3]);
  ((ushort4*)(out + (size_t)row * 1024))[t] = ov;
}

// ---------------- bf16 MFMA GEMM: C[M,N] = A[M,K] @ Bt[N,K]^T ---------------
// m97 structure: unpadded [128][32] LDS tiles, global_load_lds width-16.
__global__ __launch_bounds__(256) void gemm_bf16(
    const unsigned short* __restrict__ A, const unsigned short* __restrict__ Bt,
    const float* __restrict__ bias, const float* __restrict__ resid,
    void* __restrict__ Cout, int M, int N, int K, int mode) {
  __shared__ unsigned short As[128 * 32];
  __shared__ unsigned short Bs[128 * 32];
  const int t = threadIdx.x;
  const int m0 = blockIdx.y * 128, n0 = blockIdx.x * 128;
  const int lane = t & 63, wave = t >> 6;
  const int wm = (wave >> 1) * 64, wn = (wave & 1) * 64;
  const int l15 = lane & 15, quad = lane >> 4;

  floatx4 zero = {0.f, 0.f, 0.f, 0.f};
  floatx4 acc[4][4];
#pragma unroll
  for (int i = 0; i < 4; ++i)
#pragma unroll
    for (int j = 0; j < 4; ++j) acc[i][j] = zero;

  // staging: chunk c = wave*2+u covers rows c*16..c*16+15 (16 rows x 64 B);
  // lane i -> row c*16 + (i>>2), col (i&3)*8; LDS dest = c*512 halfs (uniform)
  const int srow = lane >> 2;          // 0..15 within chunk
  const int scol = (lane & 3) * 8;     // half offset within row
  const int c0 = wave * 2, c1 = wave * 2 + 1;

  const int KT = K >> 5;
  for (int kt = 0; kt < KT; ++kt) {
    __syncthreads();
    const unsigned short* Ag = A + (size_t)m0 * K + kt * 32 + scol;
    const unsigned short* Bg = Bt + (size_t)n0 * K + kt * 32 + scol;
    gl2lds16(Ag + (size_t)(c0 * 16 + srow) * K, &As[c0 * 512]);
    gl2lds16(Ag + (size_t)(c1 * 16 + srow) * K, &As[c1 * 512]);
    gl2lds16(Bg + (size_t)(c0 * 16 + srow) * K, &Bs[c0 * 512]);
    gl2lds16(Bg + (size_t)(c1 * 16 + srow) * K, &Bs[c1 * 512]);
    __syncthreads();
    short8 a[4], b[4];
#pragma unroll
    for (int i = 0; i < 4; ++i)
      a[i] = *(const short8*)&As[(wm + i * 16 + l15) * 32 + quad * 8];
#pragma unroll
    for (int i = 0; i < 4; ++i)
      b[i] = *(const short8*)&Bs[(wn + i * 16 + l15) * 32 + quad * 8];
#pragma unroll
    for (int i = 0; i < 4; ++i)
#pragma unroll
      for (int j = 0; j < 4; ++j)
        acc[i][j] = __builtin_amdgcn_mfma_f32_16x16x32_bf16(a[i], b[j], acc[i][j], 0, 0, 0);
  }

#pragma unroll
  for (int i = 0; i < 4; ++i)
#pragma unroll
    for (int j = 0; j < 4; ++j) {
      const int col = n0 + wn + j * 16 + l15;
      const int rb = m0 + wm + i * 16 + quad * 4;
#pragma unroll
      for (int r = 0; r < 4; ++r) {
        const int row = rb + r;
        float v = acc[i][j][r];
        if (mode == 0) {
          ((unsigned short*)Cout)[(size_t)row * N + col] = f32_to_bf16(v);
        } else if (mode == 1) {
          v += bias[col] + resid[(size_t)row * N + col];
          ((float*)Cout)[(size_t)row * N + col] = v;
        } else {
          v += bias[col];
          v = fmaxf(v, 0.f);
          ((unsigned short*)Cout)[(size_t)row * N + col] = f32_to_bf16(v);
        }
      }
    }
}

// ---------------- MFMA flash attention, causal ------------------------------
// Block: 128 q-rows, 4 waves x 32 rows. K-tile = 64 keys staged in LDS.
// Q frags in registers (scaled by 1/8). P via per-wave LDS (no barrier).
__global__ __launch_bounds__(256, 3) void flash_attn_mfma(
    const unsigned short* __restrict__ qkv,
    const unsigned short* __restrict__ vT,
    unsigned short* __restrict__ attn) {
  const int b = blockIdx.z, h = blockIdx.y, bh = b * 16 + h;
  const int qt = 15 - (int)blockIdx.x;  // biggest first
  const int q0 = qt * 128;
  const int t = threadIdx.x;
  const int wave = t >> 6, lane = t & 63;
  const int l15 = lane & 15, quad = lane >> 4;

  __shared__ unsigned short Ks[64][72];  // [key][d]
  __shared__ unsigned short Vt[64][72];  // [d][key]
  __shared__ unsigned short Ps[4][32][72];  // per-wave P [q][key]

  const size_t qbase = (size_t)b * 2048 * 3072;
  const int qrow_w = q0 + wave * 32;

  // Q A-frags from global: A[m=l15][k=quad*8+j], chunks kc*32; scale 1/8 exact
  short8 qf[2][2];
#pragma unroll
  for (int mf = 0; mf < 2; ++mf)
#pragma unroll
    for (int kc = 0; kc < 2; ++kc) {
      short8 raw = *(const short8*)(qkv + qbase +
          (size_t)(qrow_w + mf * 16 + l15) * 3072 + h * 64 + kc * 32 + quad * 8);
      short8 sc;
#pragma unroll
      for (int j = 0; j < 8; ++j)
        sc[j] = (short)f32_to_bf16(bf16_to_f32((unsigned short)raw[j]) * 0.125f);
      qf[mf][kc] = sc;
    }

  floatx4 o[2][4];
  float m_s[2][4], l_s[2][4];
#pragma unroll
  for (int mf = 0; mf < 2; ++mf)
#pragma unroll
    for (int r = 0; r < 4; ++r) {
      m_s[mf][r] = -1e30f;
      l_s[mf][r] = 0.f;
#pragma unroll
      for (int jd = 0; jd < 4; ++jd) o[mf][jd][r] = 0.f;
    }

  const int sr = t >> 3, so = (t & 7) * 8;  // staging: rows sr, sr+32, 8-short chunks

  const int ntiles = 2 * qt + 2;
  for (int kt = 0; kt < ntiles; ++kt) {
    const int k0 = kt * 64;
    __syncthreads();
    *(uint4*)&Ks[sr][so]      = *(const uint4*)(qkv + qbase + (size_t)(k0 + sr) * 3072 + 1024 + h * 64 + so);
    *(uint4*)&Ks[sr + 32][so] = *(const uint4*)(qkv + qbase + (size_t)(k0 + sr + 32) * 3072 + 1024 + h * 64 + so);
    *(uint4*)&Vt[sr][so]      = *(const uint4*)(vT + ((size_t)bh * 64 + sr) * 2048 + k0 + so);
    *(uint4*)&Vt[sr + 32][so] = *(const uint4*)(vT + ((size_t)bh * 64 + sr + 32) * 2048 + k0 + so);
    __syncthreads();
    if (k0 > qrow_w + 31) continue;  // wave-uniform: no rows need this tile

    // S = Q K^T : 16 MFMAs
    floatx4 sacc[2][4];
#pragma unroll
    for (int mf = 0; mf < 2; ++mf)
#pragma unroll
      for (int jb = 0; jb < 4; ++jb) sacc[mf][jb] = floatx4{0.f, 0.f, 0.f, 0.f};
#pragma unroll
    for (int kc = 0; kc < 2; ++kc)
#pragma unroll
      for (int jb = 0; jb < 4; ++jb) {
        short8 bf = *(const short8*)&Ks[jb * 16 + l15][kc * 32 + quad * 8];
#pragma unroll
        for (int mf = 0; mf < 2; ++mf)
          sacc[mf][jb] = __builtin_amdgcn_mfma_f32_16x16x32_bf16(qf[mf][kc], bf, sacc[mf][jb], 0, 0, 0);
      }

    // causal mask (only tiles near the diagonal)
    if (k0 + 63 > qrow_w) {
#pragma unroll
      for (int mf = 0; mf < 2; ++mf)
#pragma unroll
        for (int jb = 0; jb < 4; ++jb) {
          const int key = k0 + jb * 16 + l15;
          const int rowb = qrow_w + mf * 16 + quad * 4;
#pragma unroll
          for (int r = 0; r < 4; ++r)
            if (key > rowb + r) sacc[mf][jb][r] = -1e30f;
        }
    }

    // online softmax: stats per (mf,r) row, reduce across 16 lanes
    float mx[2][4];
#pragma unroll
    for (int mf = 0; mf < 2; ++mf)
#pragma unroll
      for (int r = 0; r < 4; ++r)
        mx[mf][r] = fmaxf(fmaxf(sacc[mf][0][r], sacc[mf][1][r]),
                          fmaxf(sacc[mf][2][r], sacc[mf][3][r]));
#pragma unroll
    for (int off = 1; off < 16; off <<= 1)
#pragma unroll
      for (int mf = 0; mf < 2; ++mf)
#pragma unroll
        for (int r = 0; r < 4; ++r) mx[mf][r] = fmaxf(mx[mf][r], __shfl_xor(mx[mf][r], off));

    float alpha[2][4], ls[2][4];
#pragma unroll
    for (int mf = 0; mf < 2; ++mf)
#pragma unroll
      for (int r = 0; r < 4; ++r) {
        float mn = fmaxf(m_s[mf][r], mx[mf][r]);
        alpha[mf][r] = __expf(m_s[mf][r] - mn);
        m_s[mf][r] = mn;
        ls[mf][r] = 0.f;
      }
#pragma unroll
    for (int mf = 0; mf < 2; ++mf)
#pragma unroll
      for (int jb = 0; jb < 4; ++jb)
#pragma unroll
        for (int r = 0; r < 4; ++r) {
          float p = __expf(sacc[mf][jb][r] - m_s[mf][r]);
          sacc[mf][jb][r] = p;
          ls[mf][r] += p;
        }
#pragma unroll
    for (int off = 1; off < 16; off <<= 1)
#pragma unroll
      for (int mf = 0; mf < 2; ++mf)
#pragma unroll
        for (int r = 0; r < 4; ++r) ls[mf][r] += __shfl_xor(ls[mf][r], off);
#pragma unroll
    for (int mf = 0; mf < 2; ++mf)
#pragma unroll
      for (int r = 0; r < 4; ++r) l_s[mf][r] = l_s[mf][r] * alpha[mf][r] + ls[mf][r];
#pragma unroll
    for (int mf = 0; mf < 2; ++mf)
#pragma unroll
      for (int jd = 0; jd < 4; ++jd)
#pragma unroll
        for (int r = 0; r < 4; ++r) o[mf][jd][r] *= alpha[mf][r];

    // P -> per-wave LDS (bf16), C-layout scatter; same-wave DS ops in-order
#pragma unroll
    for (int mf = 0; mf < 2; ++mf)
#pragma unroll
      for (int jb = 0; jb < 4; ++jb)
#pragma unroll
        for (int r = 0; r < 4; ++r)
          Ps[wave][mf * 16 + quad * 4 + r][jb * 16 + l15] = f32_to_bf16(sacc[mf][jb][r]);

    // O += P V : 16 MFMAs
#pragma unroll
    for (int kc = 0; kc < 2; ++kc) {
      short8 pf0 = *(const short8*)&Ps[wave][l15][kc * 32 + quad * 8];
      short8 pf1 = *(const short8*)&Ps[wave][16 + l15][kc * 32 + quad * 8];
#pragma unroll
      for (int jd = 0; jd < 4; ++jd) {
        short8 vf = *(const short8*)&Vt[jd * 16 + l15][kc * 32 + quad * 8];
        o[0][jd] = __builtin_amdgcn_mfma_f32_16x16x32_bf16(pf0, vf, o[0][jd], 0, 0, 0);
        o[1][jd] = __builtin_amdgcn_mfma_f32_16x16x32_bf16(pf1, vf, o[1][jd], 0, 0, 0);
      }
    }
  }

  // epilogue (note the b*2048 batch offset)
#pragma unroll
  for (int mf = 0; mf < 2; ++mf)
#pragma unroll
    for (int r = 0; r < 4; ++r) {
      const int row = b * 2048 + qrow_w + mf * 16 + quad * 4 + r;
      const float rl = 1.f / l_s[mf][r];
#pragma unroll
      for (int jd = 0; jd < 4; ++jd)
        attn[(size_t)row * 1024 + h * 64 + jd * 16 + l15] = f32_to_bf16(o[mf][jd][r] * rl);
    }
}

// ---------------------------------------------------------------------------
extern "C" void kernel_launch(void* const* d_in, const int* in_sizes, int n_in,
                              void* d_out, int out_size, void* d_ws, size_t ws_size,
                              hipStream_t stream) {
  const float* x   = (const float*)d_in[0];
  const float* Wq  = (const float*)d_in[1];
  const float* Wk  = (const float*)d_in[2];
  const float* Wv  = (const float*)d_in[3];
  const float* Wo  = (const float*)d_in[4];
  const float* bo  = (const float*)d_in[5];
  const float* W1  = (const float*)d_in[6];
  const float* b1  = (const float*)d_in[7];
  const float* W2  = (const float*)d_in[8];
  const float* b2  = (const float*)d_in[9];
  const float* g1  = (const float*)d_in[10];
  const float* be1 = (const float*)d_in[11];
  const float* g2  = (const float*)d_in[12];
  const float* be2 = (const float*)d_in[13];
  float* out = (float*)d_out;

  char* ws = (char*)d_ws;
  size_t off = 0;
  auto alloc = [&](size_t bytes) -> void* {
    void* p = ws + off;
    off += (bytes + 255) & ~(size_t)255;
    return p;
  };
  unsigned short* WqkvT = (unsigned short*)alloc(3072ull * 1024 * 2);
  unsigned short* WoT   = (unsigned short*)alloc(1024ull * 1024 * 2);
  unsigned short* W1T   = (unsigned short*)alloc(4096ull * 1024 * 2);
  unsigned short* W2T   = (unsigned short*)alloc(1024ull * 4096 * 2);
  unsigned short* nx    = (unsigned short*)alloc(4096ull * 1024 * 2);
  unsigned short* qkv   = (unsigned short*)alloc(4096ull * 3072 * 2);
  unsigned short* attn  = (unsigned short*)alloc(4096ull * 1024 * 2);
  float*          x1    = (float*)alloc(4096ull * 1024 * 4);
  unsigned short* nx2   = (unsigned short*)alloc(4096ull * 1024 * 2);
  unsigned short* hbuf  = (unsigned short*)alloc(4096ull * 4096 * 2);
  // vT [32][64][2048] bf16 (8 MB) aliases hbuf: vT dead before GEMM3 writes hbuf
  unsigned short* vT    = hbuf;

  dim3 blk(256);
  transpose_to_bf16<<<dim3(2, 32, 16), blk, 0, stream>>>(Wq, WqkvT, 1024, 64, 1024, 65536, 65536);
  transpose_to_bf16<<<dim3(2, 32, 16), blk, 0, stream>>>(Wk, WqkvT + 1024 * 1024, 1024, 64, 1024, 65536, 65536);
  transpose_to_bf16<<<dim3(2, 32, 16), blk, 0, stream>>>(Wv, WqkvT + 2 * 1024 * 1024, 1024, 64, 1024, 65536, 65536);
  transpose_to_bf16<<<dim3(32, 32, 1), blk, 0, stream>>>(Wo, WoT, 1024, 1024, 1024, 0, 0);
  transpose_to_bf16<<<dim3(128, 32, 1), blk, 0, stream>>>(W1, W1T, 1024, 4096, 1024, 0, 0);
  transpose_to_bf16<<<dim3(32, 128, 1), blk, 0, stream>>>(W2, W2T, 4096, 1024, 4096, 0, 0);

  layernorm_bf16<<<4096, blk, 0, stream>>>(x, g1, be1, nx);
  gemm_bf16<<<dim3(24, 32), blk, 0, stream>>>(nx, WqkvT, nullptr, nullptr, qkv, 4096, 3072, 1024, 0);
  transpose_v<<<dim3(64, 2, 32), blk, 0, stream>>>(qkv, vT);
  flash_attn_mfma<<<dim3(16, 16, 2), blk, 0, stream>>>(qkv, vT, attn);
  gemm_bf16<<<dim3(8, 32), blk, 0, stream>>>(attn, WoT, bo, x, x1, 4096, 1024, 1024, 1);
  layernorm_bf16<<<4096, blk, 0, stream>>>(x1, g2, be2, nx2);
  gemm_bf16<<<dim3(32, 32), blk, 0, stream>>>(nx2, W1T, b1, nullptr, hbuf, 4096, 4096, 1024, 2);
  gemm_bf16<<<dim3(8, 32), blk, 0, stream>>>(hbuf, W2T, b2, x1, out, 4096, 1024, 4096, 1);
}